// Round 7
// baseline (511.233 us; speedup 1.0000x reference)
//
#include <hip/hip_runtime.h>
#include <hip/hip_bf16.h>
#include <stdint.h>

#define DIM   3072
#define BATCH 16384

typedef __attribute__((ext_vector_type(8))) short bf16x8;
typedef __attribute__((ext_vector_type(4))) float f32x4;

__device__ __forceinline__ unsigned short f2b(float f) {
    union { float f; unsigned u; } c; c.f = f;
    unsigned u = c.u;
    unsigned r = (u + 0x7fffu + ((u >> 16) & 1u)) >> 16;
    return (unsigned short)r;
}

__device__ __forceinline__ bf16x8 cvt8(float4 a, float4 b) {
    union { unsigned short h[8]; bf16x8 v; } u;
    u.h[0] = f2b(a.x); u.h[1] = f2b(a.y); u.h[2] = f2b(a.z); u.h[3] = f2b(a.w);
    u.h[4] = f2b(b.x); u.h[5] = f2b(b.y); u.h[6] = f2b(b.z); u.h[7] = f2b(b.w);
    return u.v;
}

// ------ pre-pass: wt[u][d] = bf16(mask[u][d] * w[d][u]) ------
__global__ __launch_bounds__(256) void build_wt_kernel(const float* __restrict__ w,
                                                       const float* __restrict__ mask,
                                                       ushort* __restrict__ wt) {
    __shared__ float tile[64][65];
    const int u0 = (blockIdx.x % 48) * 64;
    const int d0 = (blockIdx.x / 48) * 64;
    const int t  = threadIdx.x;
    const int rr = t >> 4, cc = t & 15;
#pragma unroll
    for (int it = 0; it < 4; ++it) {
        int drow = it * 16 + rr;
        float4 v = *reinterpret_cast<const float4*>(&w[(size_t)(d0 + drow) * DIM + u0 + cc * 4]);
        tile[drow][cc * 4 + 0] = v.x;
        tile[drow][cc * 4 + 1] = v.y;
        tile[drow][cc * 4 + 2] = v.z;
        tile[drow][cc * 4 + 3] = v.w;
    }
    __syncthreads();
#pragma unroll
    for (int it = 0; it < 4; ++it) {
        int urow = it * 16 + rr;
        float4 mv = *reinterpret_cast<const float4*>(&mask[(size_t)(u0 + urow) * DIM + d0 + cc * 4]);
        ushort4 o;
        o.x = f2b(tile[cc * 4 + 0][urow] * mv.x);
        o.y = f2b(tile[cc * 4 + 1][urow] * mv.y);
        o.z = f2b(tile[cc * 4 + 2][urow] * mv.z);
        o.w = f2b(tile[cc * 4 + 3][urow] * mv.w);
        *reinterpret_cast<ushort4*>(&wt[(size_t)(u0 + urow) * DIM + d0 + cc * 4]) = o;
    }
}

#define GLOAD_LDS16(g, l)                                                                 \
    __builtin_amdgcn_global_load_lds((const __attribute__((address_space(1))) void*)(g),  \
                                     (__attribute__((address_space(3))) void*)(l), 16, 0, 0)

// ======================= 256² 8-phase bf16 GEMM, fused f32->bf16 A (attempt 3) =====
// A: x [BATCH][DIM] f32, converted in-kernel.  B: wt [DIM][DIM] bf16.
// 8 waves (2M x 4N), per-wave C = 128x64. BK=64, double-buffered 128 KB LDS.
// B staged via global_load_lds (pre-swizzled source).
// A staged via volatile-asm global_load_dwordx4 WITHOUT memory clobber
// (not sinkable past barriers, but ds_read/MFMA schedule freely), with
// memory-clobbered counted VMWAIT + sched_barrier only at 2 points / 4 phases.
__global__ __launch_bounds__(512, 1) void gemm8p(const float* __restrict__ X,
                                                 const ushort* __restrict__ B,
                                                 const float* __restrict__ bias,
                                                 float* __restrict__ C) {
    __shared__ ushort sh[2 * 2 * 16384];   // [buf][side A=0/B=1][256][64] : 128 KB

    const int tid  = threadIdx.x;
    const int lane = tid & 63;
    const int wid  = tid >> 6;   // 0..7
    const int wr   = wid >> 2;   // 0..1  (M)
    const int wc   = wid & 3;    // 0..3  (N)
    const int l15  = lane & 15;
    const int kg   = lane >> 4;
    const int sx   = lane & 7;   // ds_read swizzle XOR key (row&7 == l15&7)

    const int srow = lane >> 3;            // 0..7
    const int sg   = (lane & 7) ^ srow;    // pre-swizzled logical granule

    // XCD-aware bijective swizzle (gridDim.x == 768, %8 == 0)
    const int orig = blockIdx.x;
    const int wg   = (orig & 7) * (gridDim.x >> 3) + (orig >> 3);
    const int tm   = wg / 12;
    const int tn   = wg - tm * 12;
    const int brow = tm * 256, bcol = tn * 256;

    f32x4 acc[8][4] = {};
    bf16x8 a_[8], b0_[4], b1_[4];
    float4 a0v[4], a1v[4];   // in-flight A half-tiles (issue-early / write-late)

    // ---- B staging: 2 x global_load_lds, linear LDS dest, pre-swizzled source ----
#define BSTAGE(b, h, tt)                                                                   \
    do {                                                                                   \
        int _t = (tt) < 47 ? (tt) : 47;                                                    \
        int _r0 = bcol + (h) * 128 + wid * 16 + srow;                                      \
        const ushort* _g0 = B + (size_t)_r0 * DIM + _t * 64 + sg * 8;                      \
        ushort* _l0 = sh + ((b) * 2 + 1) * 16384 + (h) * 8192 + wid * 1024;                \
        GLOAD_LDS16(_g0, _l0);                                                             \
        GLOAD_LDS16(_g0 + (size_t)8 * DIM, _l0 + 512);                                     \
    } while (0)

    // ---- A staging: 4 volatile asm loads, NO memory clobber (schedulable around) ----
#define ALOAD(dst, h, tt)                                                                  \
    do {                                                                                   \
        int _t = (tt) < 47 ? (tt) : 47;                                                    \
        int _r0 = brow + (h) * 128 + wid * 16 + srow;                                      \
        const float* _g  = X + (size_t)_r0 * DIM + _t * 64 + sg * 8;                       \
        const float* _g2 = _g + (size_t)8 * DIM;                                           \
        asm volatile("global_load_dwordx4 %0, %1, off"           : "=&v"(dst[0]) : "v"(_g));  \
        asm volatile("global_load_dwordx4 %0, %1, off offset:16" : "=&v"(dst[1]) : "v"(_g));  \
        asm volatile("global_load_dwordx4 %0, %1, off"           : "=&v"(dst[2]) : "v"(_g2)); \
        asm volatile("global_load_dwordx4 %0, %1, off offset:16" : "=&v"(dst[3]) : "v"(_g2)); \
    } while (0)

    // ---- counted wait; memory clobber + sched_barrier pin stores & cvt below ----
#define VMWAIT(N)                                                                          \
    asm volatile("s_waitcnt vmcnt(" #N ")" ::: "memory");                                  \
    __builtin_amdgcn_sched_barrier(0);

    // ---- A write: cvt + 2 x ds_write_b128 at swizzled (linear-equivalent) offsets ----
#define AWRITE(src, b, h)                                                                  \
    do {                                                                                   \
        bf16x8 _w0 = cvt8(src[0], src[1]);                                                 \
        bf16x8 _w1 = cvt8(src[2], src[3]);                                                 \
        ushort* _l = sh + (b) * 32768 + (h) * 8192 + wid * 1024 + srow * 64 + (lane & 7) * 8; \
        *reinterpret_cast<bf16x8*>(_l) = _w0;                                              \
        *reinterpret_cast<bf16x8*>(_l + 512) = _w1;                                        \
    } while (0)

#define LDA(QB, QM)                                                                        \
    _Pragma("unroll") for (int fm = 0; fm < 4; ++fm)                                       \
    _Pragma("unroll") for (int ks = 0; ks < 2; ++ks)                                       \
        a_[fm * 2 + ks] = *reinterpret_cast<const bf16x8*>(                                \
            sh + (QB) * 32768 + (wr * 128 + (QM) * 64 + fm * 16 + l15) * 64 +              \
            (((ks * 4 + kg) ^ sx) * 8));

#define LDB(DST, QB, QN)                                                                   \
    _Pragma("unroll") for (int fn = 0; fn < 2; ++fn)                                       \
    _Pragma("unroll") for (int ks = 0; ks < 2; ++ks)                                       \
        DST[fn * 2 + ks] = *reinterpret_cast<const bf16x8*>(                               \
            sh + (QB) * 32768 + 16384 + (wc * 64 + (QN) * 32 + fn * 16 + l15) * 64 +       \
            (((ks * 4 + kg) ^ sx) * 8));

#define MMQ(QM, QN, BARR)                                                                  \
    _Pragma("unroll") for (int fm = 0; fm < 4; ++fm)                                       \
    _Pragma("unroll") for (int fn = 0; fn < 2; ++fn)                                       \
    _Pragma("unroll") for (int ks = 0; ks < 2; ++ks)                                       \
        acc[(QM) * 4 + fm][(QN) * 2 + fn] = __builtin_amdgcn_mfma_f32_16x16x32_bf16(       \
            a_[fm * 2 + ks], BARR[fn * 2 + ks], acc[(QM) * 4 + fm][(QN) * 2 + fn], 0, 0, 0);

#define MIDSYNC()                                                                          \
    __builtin_amdgcn_s_barrier();                                                          \
    asm volatile("s_waitcnt lgkmcnt(0)" ::: "memory");                                     \
    __builtin_amdgcn_sched_barrier(0);                                                     \
    __builtin_amdgcn_s_setprio(1);

#define ENDPHASE()                                                                         \
    __builtin_amdgcn_s_setprio(0);                                                         \
    __builtin_amdgcn_s_barrier();

    // ---- prologue ----
    // queue: a0(4), a1(4), B(t0)(4), B(t1)(4) = 16
    ALOAD(a0v, 0, 0);
    ALOAD(a1v, 1, 0);
    BSTAGE(0, 0, 0);
    BSTAGE(0, 1, 0);
    BSTAGE(1, 0, 1);
    BSTAGE(1, 1, 1);
    VMWAIT(12);                 // a0 landed
    AWRITE(a0v, 0, 0);
    VMWAIT(8);                  // a1 landed
    AWRITE(a1v, 0, 1);
    VMWAIT(4);                  // B(t0) landed; B(t1) 4 ops remain in flight
    asm volatile("s_waitcnt lgkmcnt(0)" ::: "memory");   // drain my ds_writes
    __builtin_amdgcn_s_barrier();

    // ---- main loop: 2 K-tiles per iter (buf0 = t, buf1 = t+1), 8 phases ----
    // steady-state at P1 entry: B(t+1) 4 ops in flight
    for (int t = 0; t < 48; t += 2) {
        // P1: compute t.Q(0,0)   issue A0(t+1) loads
        LDA(0, 0); LDB(b0_, 0, 0);
        ALOAD(a0v, 0, t + 1);
        MIDSYNC(); MMQ(0, 0, b0_); ENDPHASE();
        // P2: Q(0,1)             issue A1(t+1) loads
        LDB(b1_, 0, 1);
        ALOAD(a1v, 1, t + 1);
        MIDSYNC(); MMQ(0, 1, b1_); ENDPHASE();
        // P3: Q(1,0)             wait {B(t+1),a0}; stage B0(t+2)->buf0; write A0->buf1
        LDA(0, 1);
        VMWAIT(4);              // drains B(t+1)(4)+a0(4); leaves a1(4)
        BSTAGE(0, 0, t + 2);
        AWRITE(a0v, 1, 0);
        MIDSYNC(); MMQ(1, 0, b0_); ENDPHASE();
        // P4: Q(1,1)             wait a1; stage B1(t+2)->buf0; write A1->buf1
        VMWAIT(2);              // drains a1(4); leaves B0(t+2)(2)
        BSTAGE(0, 1, t + 2);
        AWRITE(a1v, 1, 1);
        MIDSYNC(); MMQ(1, 1, b1_); ENDPHASE();
        // P5: compute t+1.Q(0,0) issue A0(t+2) loads
        LDA(1, 0); LDB(b0_, 1, 0);
        ALOAD(a0v, 0, t + 2);
        MIDSYNC(); MMQ(0, 0, b0_); ENDPHASE();
        // P6: Q(0,1)             issue A1(t+2) loads
        LDB(b1_, 1, 1);
        ALOAD(a1v, 1, t + 2);
        MIDSYNC(); MMQ(0, 1, b1_); ENDPHASE();
        // P7: Q(1,0)             wait {B(t+2),a0}; stage B0(t+3)->buf1; write A0->buf0
        LDA(1, 1);
        VMWAIT(4);              // drains B(t+2)(4)+a0(4); leaves a1(4)
        BSTAGE(1, 0, t + 3);
        AWRITE(a0v, 0, 0);
        MIDSYNC(); MMQ(1, 0, b0_); ENDPHASE();
        // P8: Q(1,1)             wait a1; stage B1(t+3)->buf1; write A1->buf0
        VMWAIT(2);              // drains a1(4); leaves B0(t+3)(2)
        BSTAGE(1, 1, t + 3);
        AWRITE(a1v, 0, 1);
        MIDSYNC(); MMQ(1, 1, b1_); ENDPHASE();
    }

    // ---- epilogue: C/D layout col=lane&15, row=(lane>>4)*4+r ----
#pragma unroll
    for (int n = 0; n < 4; ++n) {
        int col = bcol + wc * 64 + n * 16 + l15;
        float bv = bias[col];
#pragma unroll
        for (int m = 0; m < 8; ++m) {
            int row0 = brow + wr * 128 + m * 16 + kg * 4;
#pragma unroll
            for (int r = 0; r < 4; ++r)
                C[(size_t)(row0 + r) * DIM + col] = acc[m][n][r] + bv;
        }
    }
#undef BSTAGE
#undef ALOAD
#undef VMWAIT
#undef AWRITE
#undef LDA
#undef LDB
#undef MMQ
#undef MIDSYNC
#undef ENDPHASE
}

extern "C" void kernel_launch(void* const* d_in, const int* in_sizes, int n_in,
                              void* d_out, int out_size, void* d_ws, size_t ws_size,
                              hipStream_t stream) {
    const float* x    = (const float*)d_in[0];
    const float* w    = (const float*)d_in[1];
    const float* bias = (const float*)d_in[2];
    const float* mask = (const float*)d_in[3];
    float* out = (float*)d_out;

    ushort* wt = (ushort*)d_ws;

    build_wt_kernel<<<48 * 48, 256, 0, stream>>>(w, mask, wt);
    gemm8p<<<(BATCH / 256) * (DIM / 256), 512, 0, stream>>>(x, wt, bias, out);
}

// Round 8
// 341.764 us; speedup vs baseline: 1.4959x; 1.4959x over previous
//
#include <hip/hip_runtime.h>
#include <hip/hip_bf16.h>
#include <stdint.h>

#define DIM   3072
#define BATCH 16384

typedef __attribute__((ext_vector_type(8))) short bf16x8;
typedef __attribute__((ext_vector_type(4))) float f32x4;

__device__ __forceinline__ unsigned short f2b(float f) {
    union { float f; unsigned u; } c; c.f = f;
    unsigned u = c.u;
    unsigned r = (u + 0x7fffu + ((u >> 16) & 1u)) >> 16;
    return (unsigned short)r;
}

// ======== merged pre-pass (R6-proven) ========
// blocks [0, 2304):           wt[u][d] = bf16(mask[u][d] * w[d][u])  (48x48 tiles)
// blocks [2304, 2304+NCVT):   xb = bf16(x), grid-strided float4
#define NWT   2304
#define NCVT  2048
__global__ __launch_bounds__(256) void prep_kernel(const float* __restrict__ w,
                                                   const float* __restrict__ mask,
                                                   const float* __restrict__ x,
                                                   ushort* __restrict__ wt,
                                                   ushort* __restrict__ xb) {
    if (blockIdx.x < NWT) {
        __shared__ float tile[64][65];
        const int u0 = (blockIdx.x % 48) * 64;
        const int d0 = (blockIdx.x / 48) * 64;
        const int t  = threadIdx.x;
        const int rr = t >> 4, cc = t & 15;
#pragma unroll
        for (int it = 0; it < 4; ++it) {
            int drow = it * 16 + rr;
            float4 v = *reinterpret_cast<const float4*>(&w[(size_t)(d0 + drow) * DIM + u0 + cc * 4]);
            tile[drow][cc * 4 + 0] = v.x;
            tile[drow][cc * 4 + 1] = v.y;
            tile[drow][cc * 4 + 2] = v.z;
            tile[drow][cc * 4 + 3] = v.w;
        }
        __syncthreads();
#pragma unroll
        for (int it = 0; it < 4; ++it) {
            int urow = it * 16 + rr;
            float4 mv = *reinterpret_cast<const float4*>(&mask[(size_t)(u0 + urow) * DIM + d0 + cc * 4]);
            ushort4 o;
            o.x = f2b(tile[cc * 4 + 0][urow] * mv.x);
            o.y = f2b(tile[cc * 4 + 1][urow] * mv.y);
            o.z = f2b(tile[cc * 4 + 2][urow] * mv.z);
            o.w = f2b(tile[cc * 4 + 3][urow] * mv.w);
            *reinterpret_cast<ushort4*>(&wt[(size_t)(u0 + urow) * DIM + d0 + cc * 4]) = o;
        }
    } else {
        const int n4 = BATCH * DIM / 4;
        const int stride = NCVT * 256;
        for (int i = (blockIdx.x - NWT) * 256 + threadIdx.x; i < n4; i += stride) {
            float4 v = reinterpret_cast<const float4*>(x)[i];
            ushort4 o;
            o.x = f2b(v.x); o.y = f2b(v.y); o.z = f2b(v.z); o.w = f2b(v.w);
            reinterpret_cast<ushort4*>(xb)[i] = o;
        }
    }
}

#define GLOAD_LDS16(g, l)                                                                 \
    __builtin_amdgcn_global_load_lds((const __attribute__((address_space(1))) void*)(g),  \
                                     (__attribute__((address_space(3))) void*)(l), 16, 0, 0)

// ======================= persistent 256² 8-phase bf16 GEMM =======================
// Inner 8-phase K-loop identical to R6. Each block processes 3 output tiles
// seamlessly: the K-loop's t+2/t+3 stages past t=47 target the NEXT tile's
// first panels (same buf parity as the prologue), so the pipeline never drains
// between tiles. Epilogue stores overlap the next tile's first phases.
__global__ __launch_bounds__(512, 1) void gemm8p(const ushort* __restrict__ A,
                                                 const ushort* __restrict__ B,
                                                 const float* __restrict__ bias,
                                                 float* __restrict__ C) {
    __shared__ ushort sh[2 * 2 * 16384];   // [buf][side A=0/B=1][256][64] : 128 KB

    const int tid  = threadIdx.x;
    const int lane = tid & 63;
    const int wid  = tid >> 6;   // 0..7
    const int wr   = wid >> 2;   // 0..1  (M)
    const int wc   = wid & 3;    // 0..3  (N)
    const int l15  = lane & 15;
    const int kg   = lane >> 4;
    const int sx   = lane & 7;   // swizzle XOR key on ds_read (row&7 == lane&7)

    const int srow = lane >> 3;            // 0..7
    const int sg   = (lane & 7) ^ srow;    // pre-swizzled source granule

    // persistent mapping: block bx on xcd = bx&7; 3 tiles, 32 per xcd per round
    const int bx  = blockIdx.x;
    const int xcd = bx & 7, loc = bx >> 3;
    int q    = xcd * 96 + loc;                 // round 0 tile id (bijective over rounds)
    int brow = (q / 12) * 256, bcol = (q % 12) * 256;
    int nrow = brow, ncol = bcol, nvalid = 0;  // next-tile coords, set per round

    f32x4 acc[8][4] = {};
    bf16x8 a_[8], b0_[4], b1_[4];
    const f32x4 fzero = {};

    // stage half-tile h of virtual K-tile tt into buf b, side (0=A,1=B).
    // tt >= 48 -> next tile's (tt-48); if no next tile, clamp to current t=47.
#define STAGE(b, side, h, tt)                                                              \
    do {                                                                                   \
        int _tt = (tt);                                                                    \
        int _t  = (_tt < 48) ? _tt : (nvalid ? _tt - 48 : 47);                             \
        int _rb = (_tt < 48) ? ((side) ? bcol : brow) : ((side) ? ncol : nrow);            \
        const ushort* _base = (side) ? B : A;                                              \
        int _r0 = _rb + (h) * 128 + wid * 16 + srow;                                       \
        const ushort* _g0 = _base + (size_t)_r0 * DIM + _t * 64 + sg * 8;                  \
        ushort* _l0 = sh + ((b) * 2 + (side)) * 16384 + (h) * 8192 + wid * 1024;           \
        GLOAD_LDS16(_g0, _l0);                                                             \
        GLOAD_LDS16(_g0 + (size_t)8 * DIM, _l0 + 512);                                     \
    } while (0)

#define LDA(QB, QM)                                                                        \
    _Pragma("unroll") for (int fm = 0; fm < 4; ++fm)                                       \
    _Pragma("unroll") for (int ks = 0; ks < 2; ++ks)                                       \
        a_[fm * 2 + ks] = *reinterpret_cast<const bf16x8*>(                                \
            sh + (QB) * 32768 + (wr * 128 + (QM) * 64 + fm * 16 + l15) * 64 +              \
            (((ks * 4 + kg) ^ sx) * 8));

#define LDB(DST, QB, QN)                                                                   \
    _Pragma("unroll") for (int fn = 0; fn < 2; ++fn)                                       \
    _Pragma("unroll") for (int ks = 0; ks < 2; ++ks)                                       \
        DST[fn * 2 + ks] = *reinterpret_cast<const bf16x8*>(                               \
            sh + (QB) * 32768 + 16384 + (wc * 64 + (QN) * 32 + fn * 16 + l15) * 64 +       \
            (((ks * 4 + kg) ^ sx) * 8));

#define MMQ(QM, QN, BARR)                                                                  \
    _Pragma("unroll") for (int fm = 0; fm < 4; ++fm)                                       \
    _Pragma("unroll") for (int fn = 0; fn < 2; ++fn)                                       \
    _Pragma("unroll") for (int ks = 0; ks < 2; ++ks)                                       \
        acc[(QM) * 4 + fm][(QN) * 2 + fn] = __builtin_amdgcn_mfma_f32_16x16x32_bf16(       \
            a_[fm * 2 + ks], BARR[fn * 2 + ks], acc[(QM) * 4 + fm][(QN) * 2 + fn], 0, 0, 0);

#define MIDSYNC()                                                                          \
    __builtin_amdgcn_s_barrier();                                                          \
    asm volatile("s_waitcnt lgkmcnt(0)" ::: "memory");                                     \
    __builtin_amdgcn_sched_barrier(0);                                                     \
    __builtin_amdgcn_s_setprio(1);

#define ENDPHASE()                                                                         \
    __builtin_amdgcn_s_setprio(0);                                                         \
    __builtin_amdgcn_s_barrier();

    // ---- prologue (tile 0): t0 fully -> buf0, B(t1) -> buf1; leave t1.B in flight ----
    STAGE(0, 0, 0, 0);
    STAGE(0, 0, 1, 0);
    STAGE(0, 1, 0, 0);
    STAGE(0, 1, 1, 0);
    STAGE(1, 1, 0, 1);
    STAGE(1, 1, 1, 1);
    asm volatile("s_waitcnt vmcnt(4)" ::: "memory");
    __builtin_amdgcn_s_barrier();

    for (int r = 0; r < 3; ++r) {
        nvalid = (r < 2);
        int qn = nvalid ? (xcd * 96 + (r + 1) * 32 + loc) : q;
        nrow = (qn / 12) * 256;
        ncol = (qn % 12) * 256;

        // per-tile bias preload (consumed in epilogue; drained by P4's vmcnt)
        float bv[4];
#pragma unroll
        for (int n = 0; n < 4; ++n) bv[n] = bias[bcol + wc * 64 + n * 16 + l15];

        // ---- main loop: 2 K-tiles (buf0 = t, buf1 = t+1), 8 phases (R6-identical) ----
        for (int t = 0; t < 48; t += 2) {
            // phase 1: tile t, Q(0,0)            stage A0(t+1) -> buf1
            LDA(0, 0); LDB(b0_, 0, 0);
            STAGE(1, 0, 0, t + 1);
            MIDSYNC(); MMQ(0, 0, b0_); ENDPHASE();
            // phase 2: Q(0,1)                    stage A1(t+1) -> buf1
            LDB(b1_, 0, 1);
            STAGE(1, 0, 1, t + 1);
            MIDSYNC(); MMQ(0, 1, b1_); ENDPHASE();
            // phase 3: Q(1,0)                    stage B0(t+2) -> buf0
            LDA(0, 1);
            STAGE(0, 1, 0, t + 2);
            MIDSYNC(); MMQ(1, 0, b0_); ENDPHASE();
            // phase 4: Q(1,1)                    stage B1(t+2) -> buf0, vmcnt
            STAGE(0, 1, 1, t + 2);
            asm volatile("s_waitcnt vmcnt(4)" ::: "memory");
            MIDSYNC(); MMQ(1, 1, b1_); ENDPHASE();
            // phase 5: tile t+1, Q(0,0)          stage A0(t+2) -> buf0
            LDA(1, 0); LDB(b0_, 1, 0);
            STAGE(0, 0, 0, t + 2);
            MIDSYNC(); MMQ(0, 0, b0_); ENDPHASE();
            // phase 6: Q(0,1)                    stage A1(t+2) -> buf0
            LDB(b1_, 1, 1);
            STAGE(0, 0, 1, t + 2);
            MIDSYNC(); MMQ(0, 1, b1_); ENDPHASE();
            // phase 7: Q(1,0)                    stage B0(t+3) -> buf1
            LDA(1, 1);
            STAGE(1, 1, 0, t + 3);
            MIDSYNC(); MMQ(1, 0, b0_); ENDPHASE();
            // phase 8: Q(1,1)                    stage B1(t+3) -> buf1, vmcnt
            STAGE(1, 1, 1, t + 3);
            asm volatile("s_waitcnt vmcnt(4)" ::: "memory");
            MIDSYNC(); MMQ(1, 1, b1_); ENDPHASE();
        }

        // ---- epilogue: C/D layout col=lane&15, row=(lane>>4)*4+rr ----
        // stores enter the vmcnt queue; they drain under the next tile's P1-P4.
#pragma unroll
        for (int n = 0; n < 4; ++n) {
            int col = bcol + wc * 64 + n * 16 + l15;
#pragma unroll
            for (int m = 0; m < 8; ++m) {
                int row0 = brow + wr * 128 + m * 16 + kg * 4;
#pragma unroll
                for (int rr = 0; rr < 4; ++rr)
                    C[(size_t)(row0 + rr) * DIM + col] = acc[m][n][rr] + bv[n];
            }
        }
        if (r < 2) {
#pragma unroll
            for (int m = 0; m < 8; ++m)
#pragma unroll
                for (int n = 0; n < 4; ++n)
                    acc[m][n] = fzero;
        }
        q = qn; brow = nrow; bcol = ncol;
    }
#undef STAGE
#undef LDA
#undef LDB
#undef MMQ
#undef MIDSYNC
#undef ENDPHASE
}

extern "C" void kernel_launch(void* const* d_in, const int* in_sizes, int n_in,
                              void* d_out, int out_size, void* d_ws, size_t ws_size,
                              hipStream_t stream) {
    const float* x    = (const float*)d_in[0];
    const float* w    = (const float*)d_in[1];
    const float* bias = (const float*)d_in[2];
    const float* mask = (const float*)d_in[3];
    float* out = (float*)d_out;

    const size_t wt_bytes = (size_t)DIM * DIM * sizeof(ushort);
    const size_t xb_off   = (wt_bytes + 255) & ~(size_t)255;

    ushort* wt = (ushort*)d_ws;
    ushort* xb = (ushort*)((char*)d_ws + xb_off);

    prep_kernel<<<NWT + NCVT, 256, 0, stream>>>(w, mask, x, wt, xb);
    gemm8p<<<256, 512, 0, stream>>>(xb, wt, bias, out);
}